// Round 10
// baseline (152.981 us; speedup 1.0000x reference)
//
#include <hip/hip_runtime.h>
#include <math.h>

// SupCR loss, MI355X. Round 10: revert GEMM to round-8 shape (128x64 band,
// 272 tiles — 64x64 retile halved MFMA-per-barrier and regressed 15-20us),
// keep round-9 wins: fused prep + rank-sort + init (1 launch), atomic-ticket
// finalize inside row_kernel. 3 launches total.
// Math identical to rounds 7-9 (fp32 scans, +64 exponent bias, symmetric
// dist, row pairs share key windows).

#define NN 2048      // N = B*V
#define BB 1024      // B
#define DD 512       // D
#define NT 256       // threads per block
#define NPREP 512    // prep blocks (4 rows each)
#define NEGINF (-INFINITY)
#define CS 64.0f     // exponent pre-scale bias

typedef short s16x8 __attribute__((ext_vector_type(8)));
typedef float f32x4 __attribute__((ext_vector_type(4)));

// row i of the virtual cf matrix lives at F + ((i%B)*2 + i/B)*D
__device__ __forceinline__ const float* cf_row(const float* F, int i) {
    return F + ((size_t)(i & (BB - 1)) * 2 + (size_t)(i >> 10)) * DD;
}

__device__ __forceinline__ unsigned bf_rne(float x) {
    const unsigned u = __float_as_uint(x);
    return (u + 0x7FFFu + ((u >> 16) & 1u)) >> 16;
}
__device__ __forceinline__ float bf_val(unsigned h) {
    return __uint_as_float(h << 16);
}

// ---- kernel 1: fused bf16 split + sqnorms + rank-sort + accum init ----
__global__ __launch_bounds__(256) void prep_kernel(const float* __restrict__ F,
                                                   const float* __restrict__ labels,
                                                   ushort* __restrict__ Ahi,
                                                   ushort* __restrict__ Alo,
                                                   float* __restrict__ sq,
                                                   float* __restrict__ slab,
                                                   int* __restrict__ sj,
                                                   double* __restrict__ accum,
                                                   unsigned* __restrict__ cnt) {
    const int t = threadIdx.x;
    if (blockIdx.x < NPREP) {
        // ---- bf16 hi/lo split + squared norms (4 rows/block) ----
        const int lane = t & 63;
        const int w = t >> 6;
        const int i = blockIdx.x * 4 + w;
        const float* src = cf_row(F, i);
        const float4 v0 = reinterpret_cast<const float4*>(src)[lane];
        const float4 v1 = reinterpret_cast<const float4*>(src)[lane + 64];
        float ss = v0.x * v0.x + v0.y * v0.y + v0.z * v0.z + v0.w * v0.w
                 + v1.x * v1.x + v1.y * v1.y + v1.z * v1.z + v1.w * v1.w;
        #pragma unroll
        for (int st = 32; st > 0; st >>= 1) ss += __shfl_down(ss, st);
        if (lane == 0) sq[i] = ss;

        const float a[8] = {v0.x, v0.y, v0.z, v0.w, v1.x, v1.y, v1.z, v1.w};
        ushort h[8], l[8];
        #pragma unroll
        for (int e = 0; e < 8; ++e) {
            const unsigned hb = bf_rne(a[e]);
            h[e] = (ushort)hb;
            l[e] = (ushort)bf_rne(a[e] - bf_val(hb));
        }
        const size_t base = (size_t)i * DD;
        *reinterpret_cast<ushort4*>(&Ahi[base + lane * 4])       = make_ushort4(h[0], h[1], h[2], h[3]);
        *reinterpret_cast<ushort4*>(&Ahi[base + 256 + lane * 4]) = make_ushort4(h[4], h[5], h[6], h[7]);
        *reinterpret_cast<ushort4*>(&Alo[base + lane * 4])       = make_ushort4(l[0], l[1], l[2], l[3]);
        *reinterpret_cast<ushort4*>(&Alo[base + 256 + lane * 4]) = make_ushort4(l[4], l[5], l[6], l[7]);
    } else {
        // ---- rank sort: 4 blocks x 256 threads, one label each ----
        __shared__ float lab[BB];
        #pragma unroll
        for (int e = 0; e < 4; ++e) lab[t + e * NT] = labels[t + e * NT];
        __syncthreads();
        const int p = (blockIdx.x - NPREP) * NT + t;
        const float L = lab[p];
        int rank = 0;
        #pragma unroll 4
        for (int q4 = 0; q4 < BB / 4; ++q4) {
            const float4 l4 = reinterpret_cast<const float4*>(lab)[q4];
            const int q = q4 * 4;
            rank += (l4.x < L) || (l4.x == L && (q + 0) < p);
            rank += (l4.y < L) || (l4.y == L && (q + 1) < p);
            rank += (l4.z < L) || (l4.z == L && (q + 2) < p);
            rank += (l4.w < L) || (l4.w == L && (q + 3) < p);
        }
        slab[2 * rank] = L; slab[2 * rank + 1] = L;
        sj[2 * rank] = p;   sj[2 * rank + 1] = p + BB;
        if (blockIdx.x == NPREP && t == 0) { *accum = 0.0; *cnt = 0u; }
    }
}

// ---------------- kernel 2: MFMA dist, symmetric 128x64 band tiles ----------
#define TM 128
#define TN 64
#define TK 32
__global__ __launch_bounds__(256) void gemm_dist_kernel(const ushort* __restrict__ Ahi,
                                                        const ushort* __restrict__ Alo,
                                                        const float* __restrict__ sq,
                                                        const int* __restrict__ sj,
                                                        float* __restrict__ distp) {
    __shared__ ushort Ah[4][TM][8];
    __shared__ ushort Al[4][TM][8];
    __shared__ ushort Bh[4][TN][8];
    __shared__ ushort Bl[4][TN][8];
    __shared__ int   sjcA[TM];
    __shared__ int   sjcB[TN];
    __shared__ float sqA[TM];
    __shared__ float sqB[TN];

    const int t = threadIdx.x;
    const int lane = t & 63;
    const int w = t >> 6;

    // tile id -> (by, bx) over the lower-triangular band: C(by)=by*(by+1)
    const int id = blockIdx.x;
    int by = (int)((__fsqrt_rn(4.0f * (float)id + 1.0f) - 1.0f) * 0.5f);
    while ((by + 1) * (by + 2) <= id) ++by;
    while (by * (by + 1) > id) --by;
    const int bx = id - by * (by + 1);          // 0 .. 2*by+1
    const int row0 = by * TM;
    const int col0 = bx * TN;
    const bool below = (bx < 2 * by);           // strictly left of diag square

    if (t < TM) {
        const int s = sj[row0 + t];
        sjcA[t] = s; sqA[t] = sq[s];
    } else if (t < TM + TN) {
        const int u = t - TM;
        const int s = sj[col0 + u];
        sjcB[u] = s; sqB[u] = sq[s];
    }
    __syncthreads();
    const int rr = t >> 2;
    const int cq = t & 3;
    const size_t gA0 = (size_t)sjcA[rr] * DD + cq * 8;
    const size_t gA1 = (size_t)sjcA[64 + rr] * DD + cq * 8;
    const size_t gB0 = (size_t)sjcB[rr] * DD + cq * 8;

    f32x4 acc[2][4] = {};
    const int m = lane & 15;
    const int q = lane >> 4;

    for (int kt = 0; kt < DD / TK; ++kt) {
        __syncthreads();
        const size_t ko = (size_t)kt * TK;
        *reinterpret_cast<int4*>(&Ah[cq][rr][0])      = *reinterpret_cast<const int4*>(&Ahi[gA0 + ko]);
        *reinterpret_cast<int4*>(&Al[cq][rr][0])      = *reinterpret_cast<const int4*>(&Alo[gA0 + ko]);
        *reinterpret_cast<int4*>(&Ah[cq][64 + rr][0]) = *reinterpret_cast<const int4*>(&Ahi[gA1 + ko]);
        *reinterpret_cast<int4*>(&Al[cq][64 + rr][0]) = *reinterpret_cast<const int4*>(&Alo[gA1 + ko]);
        *reinterpret_cast<int4*>(&Bh[cq][rr][0])      = *reinterpret_cast<const int4*>(&Ahi[gB0 + ko]);
        *reinterpret_cast<int4*>(&Bl[cq][rr][0])      = *reinterpret_cast<const int4*>(&Alo[gB0 + ko]);
        __syncthreads();

        s16x8 fah[2], fal[2], fbh[4], fbl[4];
        #pragma unroll
        for (int mt = 0; mt < 2; ++mt) {
            fah[mt] = *reinterpret_cast<const s16x8*>(&Ah[q][w * 32 + mt * 16 + m][0]);
            fal[mt] = *reinterpret_cast<const s16x8*>(&Al[q][w * 32 + mt * 16 + m][0]);
        }
        #pragma unroll
        for (int nt = 0; nt < 4; ++nt) {
            fbh[nt] = *reinterpret_cast<const s16x8*>(&Bh[q][nt * 16 + m][0]);
            fbl[nt] = *reinterpret_cast<const s16x8*>(&Bl[q][nt * 16 + m][0]);
        }
        #pragma unroll
        for (int mt = 0; mt < 2; ++mt)
            #pragma unroll
            for (int nt = 0; nt < 4; ++nt) {
                acc[mt][nt] = __builtin_amdgcn_mfma_f32_16x16x32_bf16(fah[mt], fbh[nt], acc[mt][nt], 0, 0, 0);
                acc[mt][nt] = __builtin_amdgcn_mfma_f32_16x16x32_bf16(fah[mt], fbl[nt], acc[mt][nt], 0, 0, 0);
                acc[mt][nt] = __builtin_amdgcn_mfma_f32_16x16x32_bf16(fal[mt], fbh[nt], acc[mt][nt], 0, 0, 0);
            }
    }

    #pragma unroll
    for (int mt = 0; mt < 2; ++mt) {
        const int lr0 = w * 32 + mt * 16 + q * 4;
        #pragma unroll
        for (int nt = 0; nt < 4; ++nt) {
            const int lc = nt * 16 + m;
            float o[4];
            #pragma unroll
            for (int r = 0; r < 4; ++r) {
                const float d2 = sqA[lr0 + r] + sqB[lc] - 2.0f * acc[mt][nt][r];
                o[r] = (d2 > 0.f) ? sqrtf(d2) : 0.f;
            }
            #pragma unroll
            for (int r = 0; r < 4; ++r)
                distp[(size_t)(row0 + lr0 + r) * NN + col0 + lc] = o[r];
            if (below) {
                const float4 o4 = make_float4(o[0], o[1], o[2], o[3]);
                *reinterpret_cast<float4*>(&distp[(size_t)(col0 + lc) * NN + row0 + lr0]) = o4;
            }
        }
    }
}

// ---------------- kernel 3: row-pair scans + shared windows + final ---------
__device__ __forceinline__ int bs_right(const float* key, float d, int lo, int hi) {
    while (lo < hi) {
        const int mid = (lo + hi) >> 1;
        if (key[mid] >= d) hi = mid; else lo = mid + 1;
    }
    return lo;
}
__device__ __forceinline__ int bs_left(const float* key, float d, int lo, int hi) {
    while (lo < hi) {
        const int mid = (lo + hi) >> 1;
        if (key[mid] < d) hi = mid; else lo = mid + 1;
    }
    return lo;
}

__global__ __launch_bounds__(256) void row_kernel(const float* __restrict__ distp,
                                                  const float* __restrict__ slab,
                                                  double* __restrict__ accum,
                                                  unsigned* __restrict__ cnt,
                                                  float* __restrict__ out) {
    __shared__ float key[NN];
    __shared__ float Pf[NN];
    __shared__ float Sf[NN + 1];
    __shared__ float wmxA[4], wmxB[4], wps[4], wss[4];
    __shared__ double wDA[4], wLA[4], wDB[4], wLB[4];

    const int pr = blockIdx.x;
    const int rA = 2 * pr, rB = 2 * pr + 1;
    const int t = threadIdx.x;
    const int lane = t & 63;
    const int w = t >> 6;
    const float x = slab[rA];
    const float negInvT = -1.0f / 0.07f;
    const float* drowA = &distp[(size_t)rA * NN];
    const float* drowB = &distp[(size_t)rB * NN];

    #pragma unroll
    for (int e = 0; e < 2; ++e) {
        const int p4 = t + e * NT;
        const float4 l4 = reinterpret_cast<const float4*>(slab)[p4];
        key[p4 * 4 + 0] = fabsf(l4.x - x);
        key[p4 * 4 + 1] = fabsf(l4.y - x);
        key[p4 * 4 + 2] = fabsf(l4.z - x);
        key[p4 * 4 + 3] = fabsf(l4.w - x);
    }
    const int cb = t * 8;
    float vA[8], vB[8];
    double dsumA = 0.0, dsumB = 0.0;
    float mxA = NEGINF, mxB = NEGINF;
    #pragma unroll
    for (int e = 0; e < 2; ++e) {
        const float4 a4 = reinterpret_cast<const float4*>(drowA)[2 * t + e];
        const float4 b4 = reinterpret_cast<const float4*>(drowB)[2 * t + e];
        const float av[4] = {a4.x, a4.y, a4.z, a4.w};
        const float bv[4] = {b4.x, b4.y, b4.z, b4.w};
        #pragma unroll
        for (int c = 0; c < 4; ++c) {
            const int pc = cb + e * 4 + c;
            if (pc == rA) vA[e * 4 + c] = NEGINF;
            else { const float vv = av[c] * negInvT; vA[e * 4 + c] = vv; mxA = fmaxf(mxA, vv); dsumA += (double)av[c]; }
            if (pc == rB) vB[e * 4 + c] = NEGINF;
            else { const float vv = bv[c] * negInvT; vB[e * 4 + c] = vv; mxB = fmaxf(mxB, vv); dsumB += (double)bv[c]; }
        }
    }
    #pragma unroll
    for (int st = 32; st > 0; st >>= 1) {
        mxA = fmaxf(mxA, __shfl_down(mxA, st));
        mxB = fmaxf(mxB, __shfl_down(mxB, st));
    }
    if (lane == 0) { wmxA[w] = mxA; wmxB[w] = mxB; }
    __syncthreads();   // B1
    const float MA = fmaxf(fmaxf(wmxA[0], wmxA[1]), fmaxf(wmxA[2], wmxA[3]));
    const float MB = fmaxf(fmaxf(wmxB[0], wmxB[1]), fmaxf(wmxB[2], wmxB[3]));

    // ---- window boundaries ONCE (shared by both rows) ----
    int L8[8], R8[8];
    const int a = cb, b = cb + 7;
    {
        const int le = (rA - 1 < b) ? rA - 1 : b;
        if (a <= le) {
            const float da = key[a];
            const int Ra = bs_right(key, da, rA, NN);
            int Rl = Ra;
            if (le > a) Rl = bs_right(key, key[le], rA, Ra);
            for (int p = a; p <= le; ++p) {
                const float d = key[p];
                int R;
                if (p == a) R = Ra;
                else if (p == le) R = Rl;
                else R = bs_right(key, d, Rl, Ra);
                int L = p + 1;
                while (L < rA && key[L] == d) ++L;
                L8[p - a] = L; R8[p - a] = R;
            }
        }
        const int rs = (rA + 1 > a) ? rA + 1 : a;
        if (rs <= b) {
            const float dr = key[rs];
            const int Lr = bs_left(key, dr, 0, rA);
            int Lb = Lr;
            if (b > rs) Lb = bs_left(key, key[b], 0, Lr);
            for (int p = rs; p <= b; ++p) {
                const float d = key[p];
                int L;
                if (p == rs) L = Lr;
                else if (p == b) L = Lb;
                else L = bs_left(key, d, Lb, Lr);
                int R = p;
                while (R > rA && key[R - 1] == d) --R;
                L8[p - a] = L; R8[p - a] = R;
            }
        }
        if (rA >= a && rA <= b) { L8[rA - a] = rA; R8[rA - a] = rA; }
    }

    // ================= row A =================
    double lnsumA = 0.0;
    {
        float e8[8];
        #pragma unroll
        for (int jj = 0; jj < 8; ++jj) e8[jj] = __expf(vA[jj] - MA + CS);
        {
            float run = 0.f, ex[8];
            #pragma unroll
            for (int jj = 0; jj < 8; ++jj) { ex[jj] = run; run += e8[jj]; }
            float inc = run;
            #pragma unroll
            for (int st = 1; st < 64; st <<= 1) {
                const float nm = __shfl_up(inc, st);
                if (lane >= st) inc += nm;
            }
            float xofs = __shfl_up(inc, 1);
            if (lane == 0) xofs = 0.f;
            if (lane == 63) wps[w] = inc;
            __syncthreads();   // B2
            #pragma unroll
            for (int ww = 0; ww < 3; ++ww)
                if (ww < w) xofs += wps[ww];
            #pragma unroll
            for (int jj = 0; jj < 8; ++jj) Pf[cb + jj] = ex[jj] + xofs;
        }
        {
            float run = 0.f, sx[8];
            #pragma unroll
            for (int jj = 7; jj >= 0; --jj) { run += e8[jj]; sx[jj] = run; }
            float inc = run;
            #pragma unroll
            for (int st = 1; st < 64; st <<= 1) {
                const float nm = __shfl_down(inc, st);
                if (lane + st < 64) inc += nm;
            }
            float xofs = __shfl_down(inc, 1);
            if (lane == 63) xofs = 0.f;
            if (lane == 0) wss[w] = inc;
            __syncthreads();   // B3
            #pragma unroll
            for (int ww = 1; ww < 4; ++ww)
                if (ww > w) xofs += wss[ww];
            #pragma unroll
            for (int jj = 0; jj < 8; ++jj) Sf[cb + jj] = sx[jj] + xofs;
            if (t == 0) Sf[NN] = 0.f;
        }
        __syncthreads();   // B4
        const float MBA = MA - CS;
        #pragma unroll
        for (int jj = 0; jj < 8; ++jj) {
            const int p = cb + jj;
            if (p == rA) continue;
            const float s = fmaxf(Pf[L8[jj]] + Sf[R8[jj]], 1e-38f);
            lnsumA += (double)(MBA + __logf(s));
        }
    }
    __syncthreads();   // B5

    // ================= row B =================
    double lnsumB = 0.0;
    {
        float e8[8];
        #pragma unroll
        for (int jj = 0; jj < 8; ++jj) e8[jj] = __expf(vB[jj] - MB + CS);
        {
            float run = 0.f, ex[8];
            #pragma unroll
            for (int jj = 0; jj < 8; ++jj) { ex[jj] = run; run += e8[jj]; }
            float inc = run;
            #pragma unroll
            for (int st = 1; st < 64; st <<= 1) {
                const float nm = __shfl_up(inc, st);
                if (lane >= st) inc += nm;
            }
            float xofs = __shfl_up(inc, 1);
            if (lane == 0) xofs = 0.f;
            if (lane == 63) wps[w] = inc;
            __syncthreads();   // B6
            #pragma unroll
            for (int ww = 0; ww < 3; ++ww)
                if (ww < w) xofs += wps[ww];
            #pragma unroll
            for (int jj = 0; jj < 8; ++jj) Pf[cb + jj] = ex[jj] + xofs;
        }
        {
            float run = 0.f, sx[8];
            #pragma unroll
            for (int jj = 7; jj >= 0; --jj) { run += e8[jj]; sx[jj] = run; }
            float inc = run;
            #pragma unroll
            for (int st = 1; st < 64; st <<= 1) {
                const float nm = __shfl_down(inc, st);
                if (lane + st < 64) inc += nm;
            }
            float xofs = __shfl_down(inc, 1);
            if (lane == 63) xofs = 0.f;
            if (lane == 0) wss[w] = inc;
            __syncthreads();   // B7
            #pragma unroll
            for (int ww = 1; ww < 4; ++ww)
                if (ww > w) xofs += wss[ww];
            #pragma unroll
            for (int jj = 0; jj < 8; ++jj) Sf[cb + jj] = sx[jj] + xofs;
            if (t == 0) Sf[NN] = 0.f;
        }
        __syncthreads();   // B8
        const float MBB = MB - CS;
        #pragma unroll
        for (int jj = 0; jj < 8; ++jj) {
            const int p = cb + jj;
            if (p == rB) continue;
            const float s = fmaxf(Pf[L8[jj]] + Sf[R8[jj]], 1e-38f);
            lnsumB += (double)(MBB + __logf(s));
        }
    }

    // ---- reductions + global accumulate + last-block finalize ----
    #pragma unroll
    for (int st = 32; st > 0; st >>= 1) {
        dsumA  += __shfl_down(dsumA, st);
        lnsumA += __shfl_down(lnsumA, st);
        dsumB  += __shfl_down(dsumB, st);
        lnsumB += __shfl_down(lnsumB, st);
    }
    if (lane == 0) { wDA[w] = dsumA; wLA[w] = lnsumA; wDB[w] = dsumB; wLB[w] = lnsumB; }
    __syncthreads();   // B9
    if (t == 0) {
        const double rowA = (-(wDA[0] + wDA[1] + wDA[2] + wDA[3]) / 0.07)
                          - (wLA[0] + wLA[1] + wLA[2] + wLA[3]);
        const double rowB = (-(wDB[0] + wDB[1] + wDB[2] + wDB[3]) / 0.07)
                          - (wLB[0] + wLB[1] + wLB[2] + wLB[3]);
        atomicAdd(accum, rowA + rowB);
        __threadfence();
        const unsigned old = atomicAdd(cnt, 1u);
        if (old == (unsigned)(gridDim.x - 1)) {
            const double tot = atomicAdd(accum, 0.0);   // atomic read: all adds done
            out[0] = (float)(-tot / ((double)NN * (double)(NN - 1)));
        }
    }
}

extern "C" void kernel_launch(void* const* d_in, const int* in_sizes, int n_in,
                              void* d_out, int out_size, void* d_ws, size_t ws_size,
                              hipStream_t stream) {
    const float* features = (const float*)d_in[0];  // [1024, 2, 512] fp32
    const float* labels   = (const float*)d_in[1];  // [1024] fp32
    float* out = (float*)d_out;

    char* ws = (char*)d_ws;
    double*   accum = (double*)  (ws + 0);
    unsigned* cnt   = (unsigned*)(ws + 8);
    float*    sq    = (float*)   (ws + 64);
    float*    slab  = (float*)   (ws + 64 + 8192);
    int*      sj    = (int*)     (ws + 64 + 16384);
    ushort*   Ahi   = (ushort*)  (ws + 24640);
    ushort*   Alo   = (ushort*)  (ws + 24640 + (size_t)NN * DD * 2);
    float*    distp = (float*)   (ws + 24640 + (size_t)NN * DD * 4);

    prep_kernel<<<NPREP + 4, NT, 0, stream>>>(features, labels, Ahi, Alo, sq,
                                              slab, sj, accum, cnt);
    gemm_dist_kernel<<<16 * 17, NT, 0, stream>>>(Ahi, Alo, sq, sj, distp);  // 272 band tiles
    row_kernel<<<NN / 2, NT, 0, stream>>>(distp, slab, accum, cnt, out);
}

// Round 11
// 137.534 us; speedup vs baseline: 1.1123x; 1.1123x over previous
//
#include <hip/hip_runtime.h>
#include <math.h>

// SupCR loss, MI355X. Round 11: revert round-9/10 shared changes (fused prep,
// atomic+threadfence finalize) which cost ~19us vs round 8 — likely the
// device-scope fence's buffer_inv thrashing L2 under 1024 concurrent blocks.
// Keep: rank sort (parallel, standalone) and 64x64 lower-tri GEMM (528 blocks
// beat 272x128x64 on load balance in the 9-vs-10 A/B).
// Structure: prep, rank_sort, gemm(64x64 sym), row_pair -> rowval, finalize.

#define NN 2048      // N = B*V
#define BB 1024      // B
#define DD 512       // D
#define NT 256       // threads per block
#define NEGINF (-INFINITY)
#define CS 64.0f     // exponent pre-scale bias

typedef short s16x8 __attribute__((ext_vector_type(8)));
typedef float f32x4 __attribute__((ext_vector_type(4)));

// row i of the virtual cf matrix lives at F + ((i%B)*2 + i/B)*D
__device__ __forceinline__ const float* cf_row(const float* F, int i) {
    return F + ((size_t)(i & (BB - 1)) * 2 + (size_t)(i >> 10)) * DD;
}

__device__ __forceinline__ unsigned bf_rne(float x) {
    const unsigned u = __float_as_uint(x);
    return (u + 0x7FFFu + ((u >> 16) & 1u)) >> 16;
}
__device__ __forceinline__ float bf_val(unsigned h) {
    return __uint_as_float(h << 16);
}

// ---------------- kernel 0: rank sort (4 blocks, parallel) ----------------
__global__ __launch_bounds__(256) void rank_sort_kernel(const float* __restrict__ labels,
                                                        float* __restrict__ slab,
                                                        int* __restrict__ sj) {
    __shared__ float lab[BB];
    const int t = threadIdx.x;
    #pragma unroll
    for (int e = 0; e < 4; ++e) lab[t + e * NT] = labels[t + e * NT];
    __syncthreads();
    const int p = blockIdx.x * NT + t;
    const float L = lab[p];
    int rank = 0;
    #pragma unroll 4
    for (int q4 = 0; q4 < BB / 4; ++q4) {
        const float4 l4 = reinterpret_cast<const float4*>(lab)[q4];
        const int q = q4 * 4;
        rank += (l4.x < L) || (l4.x == L && (q + 0) < p);
        rank += (l4.y < L) || (l4.y == L && (q + 1) < p);
        rank += (l4.z < L) || (l4.z == L && (q + 2) < p);
        rank += (l4.w < L) || (l4.w == L && (q + 3) < p);
    }
    slab[2 * rank] = L; slab[2 * rank + 1] = L;
    sj[2 * rank] = p;   sj[2 * rank + 1] = p + BB;
}

// ---------------- kernel 1: bf16 hi/lo split + squared norms ----------------
__global__ __launch_bounds__(256) void prep_split_kernel(const float* __restrict__ F,
                                                         ushort* __restrict__ Ahi,
                                                         ushort* __restrict__ Alo,
                                                         float* __restrict__ sq) {
    const int t = threadIdx.x;
    const int lane = t & 63;
    const int w = t >> 6;
    const int i = blockIdx.x * 4 + w;
    const float* src = cf_row(F, i);
    const float4 v0 = reinterpret_cast<const float4*>(src)[lane];
    const float4 v1 = reinterpret_cast<const float4*>(src)[lane + 64];
    float ss = v0.x * v0.x + v0.y * v0.y + v0.z * v0.z + v0.w * v0.w
             + v1.x * v1.x + v1.y * v1.y + v1.z * v1.z + v1.w * v1.w;
    #pragma unroll
    for (int st = 32; st > 0; st >>= 1) ss += __shfl_down(ss, st);
    if (lane == 0) sq[i] = ss;

    const float a[8] = {v0.x, v0.y, v0.z, v0.w, v1.x, v1.y, v1.z, v1.w};
    ushort h[8], l[8];
    #pragma unroll
    for (int e = 0; e < 8; ++e) {
        const unsigned hb = bf_rne(a[e]);
        h[e] = (ushort)hb;
        l[e] = (ushort)bf_rne(a[e] - bf_val(hb));
    }
    const size_t base = (size_t)i * DD;
    *reinterpret_cast<ushort4*>(&Ahi[base + lane * 4])       = make_ushort4(h[0], h[1], h[2], h[3]);
    *reinterpret_cast<ushort4*>(&Ahi[base + 256 + lane * 4]) = make_ushort4(h[4], h[5], h[6], h[7]);
    *reinterpret_cast<ushort4*>(&Alo[base + lane * 4])       = make_ushort4(l[0], l[1], l[2], l[3]);
    *reinterpret_cast<ushort4*>(&Alo[base + 256 + lane * 4]) = make_ushort4(l[4], l[5], l[6], l[7]);
}

// ---------------- kernel 2: MFMA dist, symmetric 64x64 lower tiles ----------
#define GT 64
#define TK 32
__global__ __launch_bounds__(256) void gemm_dist_kernel(const ushort* __restrict__ Ahi,
                                                        const ushort* __restrict__ Alo,
                                                        const float* __restrict__ sq,
                                                        const int* __restrict__ sj,
                                                        float* __restrict__ distp) {
    __shared__ ushort Ah[4][GT][8];
    __shared__ ushort Al[4][GT][8];
    __shared__ ushort Bh[4][GT][8];
    __shared__ ushort Bl[4][GT][8];
    __shared__ int   sjcA[GT];
    __shared__ int   sjcB[GT];
    __shared__ float sqA[GT];
    __shared__ float sqB[GT];

    const int t = threadIdx.x;
    const int lane = t & 63;
    const int w = t >> 6;

    // tile id -> (by, bx) over lower triangle incl. diagonal: T(by)=by(by+1)/2
    const int id = blockIdx.x;
    int by = (int)((__fsqrt_rn(8.0f * (float)id + 1.0f) - 1.0f) * 0.5f);
    while ((by + 1) * (by + 2) / 2 <= id) ++by;
    while (by * (by + 1) / 2 > id) --by;
    const int bx = id - by * (by + 1) / 2;      // 0..by
    const int row0 = by * GT;
    const int col0 = bx * GT;
    const bool diag = (bx == by);

    if (t < GT) {
        const int s = sj[row0 + t];
        sjcA[t] = s; sqA[t] = sq[s];
    } else if (t < 2 * GT) {
        const int u = t - GT;
        const int s = sj[col0 + u];
        sjcB[u] = s; sqB[u] = sq[s];
    }
    __syncthreads();
    const int rr = t >> 2;
    const int cq = t & 3;
    const size_t gA = (size_t)sjcA[rr] * DD + cq * 8;
    const size_t gB = (size_t)sjcB[rr] * DD + cq * 8;

    f32x4 acc[4] = {};
    const int m = lane & 15;
    const int q = lane >> 4;

    for (int kt = 0; kt < DD / TK; ++kt) {
        __syncthreads();
        const size_t ko = (size_t)kt * TK;
        *reinterpret_cast<int4*>(&Ah[cq][rr][0]) = *reinterpret_cast<const int4*>(&Ahi[gA + ko]);
        *reinterpret_cast<int4*>(&Al[cq][rr][0]) = *reinterpret_cast<const int4*>(&Alo[gA + ko]);
        *reinterpret_cast<int4*>(&Bh[cq][rr][0]) = *reinterpret_cast<const int4*>(&Ahi[gB + ko]);
        *reinterpret_cast<int4*>(&Bl[cq][rr][0]) = *reinterpret_cast<const int4*>(&Alo[gB + ko]);
        __syncthreads();

        const s16x8 fah = *reinterpret_cast<const s16x8*>(&Ah[q][w * 16 + m][0]);
        const s16x8 fal = *reinterpret_cast<const s16x8*>(&Al[q][w * 16 + m][0]);
        s16x8 fbh[4], fbl[4];
        #pragma unroll
        for (int nt = 0; nt < 4; ++nt) {
            fbh[nt] = *reinterpret_cast<const s16x8*>(&Bh[q][nt * 16 + m][0]);
            fbl[nt] = *reinterpret_cast<const s16x8*>(&Bl[q][nt * 16 + m][0]);
        }
        #pragma unroll
        for (int nt = 0; nt < 4; ++nt) {
            acc[nt] = __builtin_amdgcn_mfma_f32_16x16x32_bf16(fah, fbh[nt], acc[nt], 0, 0, 0);
            acc[nt] = __builtin_amdgcn_mfma_f32_16x16x32_bf16(fah, fbl[nt], acc[nt], 0, 0, 0);
            acc[nt] = __builtin_amdgcn_mfma_f32_16x16x32_bf16(fal, fbh[nt], acc[nt], 0, 0, 0);
        }
    }

    const int lr0 = w * 16 + q * 4;
    #pragma unroll
    for (int nt = 0; nt < 4; ++nt) {
        const int lc = nt * 16 + m;
        float o[4];
        #pragma unroll
        for (int r = 0; r < 4; ++r) {
            const float d2 = sqA[lr0 + r] + sqB[lc] - 2.0f * acc[nt][r];
            o[r] = (d2 > 0.f) ? sqrtf(d2) : 0.f;
        }
        #pragma unroll
        for (int r = 0; r < 4; ++r)
            distp[(size_t)(row0 + lr0 + r) * NN + col0 + lc] = o[r];
        if (!diag) {
            const float4 o4 = make_float4(o[0], o[1], o[2], o[3]);
            *reinterpret_cast<float4*>(&distp[(size_t)(col0 + lc) * NN + row0 + lr0]) = o4;
        }
    }
}

// ---------------- kernel 3: row-pair scans + shared windows ----------------
__device__ __forceinline__ int bs_right(const float* key, float d, int lo, int hi) {
    while (lo < hi) {
        const int mid = (lo + hi) >> 1;
        if (key[mid] >= d) hi = mid; else lo = mid + 1;
    }
    return lo;
}
__device__ __forceinline__ int bs_left(const float* key, float d, int lo, int hi) {
    while (lo < hi) {
        const int mid = (lo + hi) >> 1;
        if (key[mid] < d) hi = mid; else lo = mid + 1;
    }
    return lo;
}

__global__ __launch_bounds__(256) void row_kernel(const float* __restrict__ distp,
                                                  const float* __restrict__ slab,
                                                  double* __restrict__ rowval) {
    __shared__ float key[NN];
    __shared__ float Pf[NN];
    __shared__ float Sf[NN + 1];
    __shared__ float wmxA[4], wmxB[4], wps[4], wss[4];
    __shared__ double wDA[4], wLA[4], wDB[4], wLB[4];

    const int pr = blockIdx.x;
    const int rA = 2 * pr, rB = 2 * pr + 1;
    const int t = threadIdx.x;
    const int lane = t & 63;
    const int w = t >> 6;
    const float x = slab[rA];
    const float negInvT = -1.0f / 0.07f;
    const float* drowA = &distp[(size_t)rA * NN];
    const float* drowB = &distp[(size_t)rB * NN];

    #pragma unroll
    for (int e = 0; e < 2; ++e) {
        const int p4 = t + e * NT;
        const float4 l4 = reinterpret_cast<const float4*>(slab)[p4];
        key[p4 * 4 + 0] = fabsf(l4.x - x);
        key[p4 * 4 + 1] = fabsf(l4.y - x);
        key[p4 * 4 + 2] = fabsf(l4.z - x);
        key[p4 * 4 + 3] = fabsf(l4.w - x);
    }
    const int cb = t * 8;
    float vA[8], vB[8];
    double dsumA = 0.0, dsumB = 0.0;
    float mxA = NEGINF, mxB = NEGINF;
    #pragma unroll
    for (int e = 0; e < 2; ++e) {
        const float4 a4 = reinterpret_cast<const float4*>(drowA)[2 * t + e];
        const float4 b4 = reinterpret_cast<const float4*>(drowB)[2 * t + e];
        const float av[4] = {a4.x, a4.y, a4.z, a4.w};
        const float bv[4] = {b4.x, b4.y, b4.z, b4.w};
        #pragma unroll
        for (int c = 0; c < 4; ++c) {
            const int pc = cb + e * 4 + c;
            if (pc == rA) vA[e * 4 + c] = NEGINF;
            else { const float vv = av[c] * negInvT; vA[e * 4 + c] = vv; mxA = fmaxf(mxA, vv); dsumA += (double)av[c]; }
            if (pc == rB) vB[e * 4 + c] = NEGINF;
            else { const float vv = bv[c] * negInvT; vB[e * 4 + c] = vv; mxB = fmaxf(mxB, vv); dsumB += (double)bv[c]; }
        }
    }
    #pragma unroll
    for (int st = 32; st > 0; st >>= 1) {
        mxA = fmaxf(mxA, __shfl_down(mxA, st));
        mxB = fmaxf(mxB, __shfl_down(mxB, st));
    }
    if (lane == 0) { wmxA[w] = mxA; wmxB[w] = mxB; }
    __syncthreads();   // B1
    const float MA = fmaxf(fmaxf(wmxA[0], wmxA[1]), fmaxf(wmxA[2], wmxA[3]));
    const float MB = fmaxf(fmaxf(wmxB[0], wmxB[1]), fmaxf(wmxB[2], wmxB[3]));

    // ---- window boundaries ONCE (shared by both rows) ----
    int L8[8], R8[8];
    const int a = cb, b = cb + 7;
    {
        const int le = (rA - 1 < b) ? rA - 1 : b;
        if (a <= le) {
            const float da = key[a];
            const int Ra = bs_right(key, da, rA, NN);
            int Rl = Ra;
            if (le > a) Rl = bs_right(key, key[le], rA, Ra);
            for (int p = a; p <= le; ++p) {
                const float d = key[p];
                int R;
                if (p == a) R = Ra;
                else if (p == le) R = Rl;
                else R = bs_right(key, d, Rl, Ra);
                int L = p + 1;
                while (L < rA && key[L] == d) ++L;
                L8[p - a] = L; R8[p - a] = R;
            }
        }
        const int rs = (rA + 1 > a) ? rA + 1 : a;
        if (rs <= b) {
            const float dr = key[rs];
            const int Lr = bs_left(key, dr, 0, rA);
            int Lb = Lr;
            if (b > rs) Lb = bs_left(key, key[b], 0, Lr);
            for (int p = rs; p <= b; ++p) {
                const float d = key[p];
                int L;
                if (p == rs) L = Lr;
                else if (p == b) L = Lb;
                else L = bs_left(key, d, Lb, Lr);
                int R = p;
                while (R > rA && key[R - 1] == d) --R;
                L8[p - a] = L; R8[p - a] = R;
            }
        }
        if (rA >= a && rA <= b) { L8[rA - a] = rA; R8[rA - a] = rA; }
    }

    // ================= row A =================
    double lnsumA = 0.0;
    {
        float e8[8];
        #pragma unroll
        for (int jj = 0; jj < 8; ++jj) e8[jj] = __expf(vA[jj] - MA + CS);
        {
            float run = 0.f, ex[8];
            #pragma unroll
            for (int jj = 0; jj < 8; ++jj) { ex[jj] = run; run += e8[jj]; }
            float inc = run;
            #pragma unroll
            for (int st = 1; st < 64; st <<= 1) {
                const float nm = __shfl_up(inc, st);
                if (lane >= st) inc += nm;
            }
            float xofs = __shfl_up(inc, 1);
            if (lane == 0) xofs = 0.f;
            if (lane == 63) wps[w] = inc;
            __syncthreads();   // B2
            #pragma unroll
            for (int ww = 0; ww < 3; ++ww)
                if (ww < w) xofs += wps[ww];
            #pragma unroll
            for (int jj = 0; jj < 8; ++jj) Pf[cb + jj] = ex[jj] + xofs;
        }
        {
            float run = 0.f, sx[8];
            #pragma unroll
            for (int jj = 7; jj >= 0; --jj) { run += e8[jj]; sx[jj] = run; }
            float inc = run;
            #pragma unroll
            for (int st = 1; st < 64; st <<= 1) {
                const float nm = __shfl_down(inc, st);
                if (lane + st < 64) inc += nm;
            }
            float xofs = __shfl_down(inc, 1);
            if (lane == 63) xofs = 0.f;
            if (lane == 0) wss[w] = inc;
            __syncthreads();   // B3
            #pragma unroll
            for (int ww = 1; ww < 4; ++ww)
                if (ww > w) xofs += wss[ww];
            #pragma unroll
            for (int jj = 0; jj < 8; ++jj) Sf[cb + jj] = sx[jj] + xofs;
            if (t == 0) Sf[NN] = 0.f;
        }
        __syncthreads();   // B4
        const float MBA = MA - CS;
        #pragma unroll
        for (int jj = 0; jj < 8; ++jj) {
            const int p = cb + jj;
            if (p == rA) continue;
            const float s = fmaxf(Pf[L8[jj]] + Sf[R8[jj]], 1e-38f);
            lnsumA += (double)(MBA + __logf(s));
        }
    }
    __syncthreads();   // B5

    // ================= row B =================
    double lnsumB = 0.0;
    {
        float e8[8];
        #pragma unroll
        for (int jj = 0; jj < 8; ++jj) e8[jj] = __expf(vB[jj] - MB + CS);
        {
            float run = 0.f, ex[8];
            #pragma unroll
            for (int jj = 0; jj < 8; ++jj) { ex[jj] = run; run += e8[jj]; }
            float inc = run;
            #pragma unroll
            for (int st = 1; st < 64; st <<= 1) {
                const float nm = __shfl_up(inc, st);
                if (lane >= st) inc += nm;
            }
            float xofs = __shfl_up(inc, 1);
            if (lane == 0) xofs = 0.f;
            if (lane == 63) wps[w] = inc;
            __syncthreads();   // B6
            #pragma unroll
            for (int ww = 0; ww < 3; ++ww)
                if (ww < w) xofs += wps[ww];
            #pragma unroll
            for (int jj = 0; jj < 8; ++jj) Pf[cb + jj] = ex[jj] + xofs;
        }
        {
            float run = 0.f, sx[8];
            #pragma unroll
            for (int jj = 7; jj >= 0; --jj) { run += e8[jj]; sx[jj] = run; }
            float inc = run;
            #pragma unroll
            for (int st = 1; st < 64; st <<= 1) {
                const float nm = __shfl_down(inc, st);
                if (lane + st < 64) inc += nm;
            }
            float xofs = __shfl_down(inc, 1);
            if (lane == 63) xofs = 0.f;
            if (lane == 0) wss[w] = inc;
            __syncthreads();   // B7
            #pragma unroll
            for (int ww = 1; ww < 4; ++ww)
                if (ww > w) xofs += wss[ww];
            #pragma unroll
            for (int jj = 0; jj < 8; ++jj) Sf[cb + jj] = sx[jj] + xofs;
            if (t == 0) Sf[NN] = 0.f;
        }
        __syncthreads();   // B8
        const float MBB = MB - CS;
        #pragma unroll
        for (int jj = 0; jj < 8; ++jj) {
            const int p = cb + jj;
            if (p == rB) continue;
            const float s = fmaxf(Pf[L8[jj]] + Sf[R8[jj]], 1e-38f);
            lnsumB += (double)(MBB + __logf(s));
        }
    }

    // ---- reductions ----
    #pragma unroll
    for (int st = 32; st > 0; st >>= 1) {
        dsumA  += __shfl_down(dsumA, st);
        lnsumA += __shfl_down(lnsumA, st);
        dsumB  += __shfl_down(dsumB, st);
        lnsumB += __shfl_down(lnsumB, st);
    }
    if (lane == 0) { wDA[w] = dsumA; wLA[w] = lnsumA; wDB[w] = dsumB; wLB[w] = lnsumB; }
    __syncthreads();   // B9
    if (t == 0) {
        rowval[rA] = (-(wDA[0] + wDA[1] + wDA[2] + wDA[3]) / 0.07)
                   - (wLA[0] + wLA[1] + wLA[2] + wLA[3]);
        rowval[rB] = (-(wDB[0] + wDB[1] + wDB[2] + wDB[3]) / 0.07)
                   - (wLB[0] + wLB[1] + wLB[2] + wLB[3]);
    }
}

// ---------------- kernel 4: final mean ----------------
__global__ __launch_bounds__(256) void finalize_kernel(const double* __restrict__ rowval,
                                                       float* __restrict__ out) {
    __shared__ double red[NT];
    const int t = threadIdx.x;
    double s = 0.0;
    for (int j = t; j < NN; j += NT) s += rowval[j];
    red[t] = s;
    __syncthreads();
    for (int ofs = NT / 2; ofs > 0; ofs >>= 1) {
        if (t < ofs) red[t] += red[t + ofs];
        __syncthreads();
    }
    if (t == 0) {
        out[0] = (float)(-red[0] / ((double)NN * (double)(NN - 1)));
    }
}

extern "C" void kernel_launch(void* const* d_in, const int* in_sizes, int n_in,
                              void* d_out, int out_size, void* d_ws, size_t ws_size,
                              hipStream_t stream) {
    const float* features = (const float*)d_in[0];  // [1024, 2, 512] fp32
    const float* labels   = (const float*)d_in[1];  // [1024] fp32
    float* out = (float*)d_out;

    char* ws = (char*)d_ws;
    size_t off = 0;
    float*  sq     = (float*) (ws + off); off += NN * sizeof(float);
    float*  slab   = (float*) (ws + off); off += NN * sizeof(float);
    int*    sj     = (int*)   (ws + off); off += NN * sizeof(int);
    double* rowval = (double*)(ws + off); off += NN * sizeof(double);
    ushort* Ahi    = (ushort*)(ws + off); off += (size_t)NN * DD * sizeof(ushort);
    ushort* Alo    = (ushort*)(ws + off); off += (size_t)NN * DD * sizeof(ushort);
    float*  distp  = (float*) (ws + off); off += (size_t)NN * NN * sizeof(float);

    rank_sort_kernel<<<4, NT, 0, stream>>>(labels, slab, sj);
    prep_split_kernel<<<NN / 4, NT, 0, stream>>>(features, Ahi, Alo, sq);
    gemm_dist_kernel<<<32 * 33 / 2, NT, 0, stream>>>(Ahi, Alo, sq, sj, distp);
    row_kernel<<<NN / 2, NT, 0, stream>>>(distp, slab, rowval);
    finalize_kernel<<<1, NT, 0, stream>>>(rowval, out);
}

// Round 12
// 135.586 us; speedup vs baseline: 1.1283x; 1.0144x over previous
//
#include <hip/hip_runtime.h>
#include <math.h>

// SupCR loss, MI355X. Round 12:
//  - prep + rank-sort fused again (one launch, 516 blocks) but WITHOUT the
//    atomic/threadfence finalize (R9's regression suspect). Attribution test.
//  - GEMM: double-buffered LDS, ONE barrier per K-step; kt+1 global loads
//    issued before kt's MFMA block (L2-hit latency hides under 12 MFMAs).
// row_kernel / finalize unchanged from round 11.

#define NN 2048      // N = B*V
#define BB 1024      // B
#define DD 512       // D
#define NT 256       // threads per block
#define NPREP 512    // prep blocks (4 rows each)
#define NEGINF (-INFINITY)
#define CS 64.0f     // exponent pre-scale bias

typedef short s16x8 __attribute__((ext_vector_type(8)));
typedef float f32x4 __attribute__((ext_vector_type(4)));

// row i of the virtual cf matrix lives at F + ((i%B)*2 + i/B)*D
__device__ __forceinline__ const float* cf_row(const float* F, int i) {
    return F + ((size_t)(i & (BB - 1)) * 2 + (size_t)(i >> 10)) * DD;
}

__device__ __forceinline__ unsigned bf_rne(float x) {
    const unsigned u = __float_as_uint(x);
    return (u + 0x7FFFu + ((u >> 16) & 1u)) >> 16;
}
__device__ __forceinline__ float bf_val(unsigned h) {
    return __uint_as_float(h << 16);
}

// ---- kernel 1: fused bf16 split + sqnorms + rank-sort (NO atomics) ----
__global__ __launch_bounds__(256) void prep_kernel(const float* __restrict__ F,
                                                   const float* __restrict__ labels,
                                                   ushort* __restrict__ Ahi,
                                                   ushort* __restrict__ Alo,
                                                   float* __restrict__ sq,
                                                   float* __restrict__ slab,
                                                   int* __restrict__ sj) {
    const int t = threadIdx.x;
    if (blockIdx.x < NPREP) {
        const int lane = t & 63;
        const int w = t >> 6;
        const int i = blockIdx.x * 4 + w;
        const float* src = cf_row(F, i);
        const float4 v0 = reinterpret_cast<const float4*>(src)[lane];
        const float4 v1 = reinterpret_cast<const float4*>(src)[lane + 64];
        float ss = v0.x * v0.x + v0.y * v0.y + v0.z * v0.z + v0.w * v0.w
                 + v1.x * v1.x + v1.y * v1.y + v1.z * v1.z + v1.w * v1.w;
        #pragma unroll
        for (int st = 32; st > 0; st >>= 1) ss += __shfl_down(ss, st);
        if (lane == 0) sq[i] = ss;

        const float a[8] = {v0.x, v0.y, v0.z, v0.w, v1.x, v1.y, v1.z, v1.w};
        ushort h[8], l[8];
        #pragma unroll
        for (int e = 0; e < 8; ++e) {
            const unsigned hb = bf_rne(a[e]);
            h[e] = (ushort)hb;
            l[e] = (ushort)bf_rne(a[e] - bf_val(hb));
        }
        const size_t base = (size_t)i * DD;
        *reinterpret_cast<ushort4*>(&Ahi[base + lane * 4])       = make_ushort4(h[0], h[1], h[2], h[3]);
        *reinterpret_cast<ushort4*>(&Ahi[base + 256 + lane * 4]) = make_ushort4(h[4], h[5], h[6], h[7]);
        *reinterpret_cast<ushort4*>(&Alo[base + lane * 4])       = make_ushort4(l[0], l[1], l[2], l[3]);
        *reinterpret_cast<ushort4*>(&Alo[base + 256 + lane * 4]) = make_ushort4(l[4], l[5], l[6], l[7]);
    } else {
        __shared__ float lab[BB];
        #pragma unroll
        for (int e = 0; e < 4; ++e) lab[t + e * NT] = labels[t + e * NT];
        __syncthreads();
        const int p = (blockIdx.x - NPREP) * NT + t;
        const float L = lab[p];
        int rank = 0;
        #pragma unroll 4
        for (int q4 = 0; q4 < BB / 4; ++q4) {
            const float4 l4 = reinterpret_cast<const float4*>(lab)[q4];
            const int q = q4 * 4;
            rank += (l4.x < L) || (l4.x == L && (q + 0) < p);
            rank += (l4.y < L) || (l4.y == L && (q + 1) < p);
            rank += (l4.z < L) || (l4.z == L && (q + 2) < p);
            rank += (l4.w < L) || (l4.w == L && (q + 3) < p);
        }
        slab[2 * rank] = L; slab[2 * rank + 1] = L;
        sj[2 * rank] = p;   sj[2 * rank + 1] = p + BB;
    }
}

// -------- kernel 2: MFMA dist, symmetric 64x64 tiles, double-buffered -------
#define GT 64
#define TK 32
__global__ __launch_bounds__(256) void gemm_dist_kernel(const ushort* __restrict__ Ahi,
                                                        const ushort* __restrict__ Alo,
                                                        const float* __restrict__ sq,
                                                        const int* __restrict__ sj,
                                                        float* __restrict__ distp) {
    __shared__ ushort Ah[2][4][GT][8];
    __shared__ ushort Al[2][4][GT][8];
    __shared__ ushort Bh[2][4][GT][8];
    __shared__ ushort Bl[2][4][GT][8];
    __shared__ int   sjcA[GT];
    __shared__ int   sjcB[GT];
    __shared__ float sqA[GT];
    __shared__ float sqB[GT];

    const int t = threadIdx.x;
    const int lane = t & 63;
    const int w = t >> 6;

    // tile id -> (by, bx) over lower triangle incl. diagonal
    const int id = blockIdx.x;
    int by = (int)((__fsqrt_rn(8.0f * (float)id + 1.0f) - 1.0f) * 0.5f);
    while ((by + 1) * (by + 2) / 2 <= id) ++by;
    while (by * (by + 1) / 2 > id) --by;
    const int bx = id - by * (by + 1) / 2;      // 0..by
    const int row0 = by * GT;
    const int col0 = bx * GT;
    const bool diag = (bx == by);

    if (t < GT) {
        const int s = sj[row0 + t];
        sjcA[t] = s; sqA[t] = sq[s];
    } else if (t < 2 * GT) {
        const int u = t - GT;
        const int s = sj[col0 + u];
        sjcB[u] = s; sqB[u] = sq[s];
    }
    __syncthreads();
    const int rr = t >> 2;
    const int cq = t & 3;
    const size_t gA = (size_t)sjcA[rr] * DD + cq * 8;
    const size_t gB = (size_t)sjcB[rr] * DD + cq * 8;

    // stage kt=0 into buffer 0
    {
        *reinterpret_cast<int4*>(&Ah[0][cq][rr][0]) = *reinterpret_cast<const int4*>(&Ahi[gA]);
        *reinterpret_cast<int4*>(&Al[0][cq][rr][0]) = *reinterpret_cast<const int4*>(&Alo[gA]);
        *reinterpret_cast<int4*>(&Bh[0][cq][rr][0]) = *reinterpret_cast<const int4*>(&Ahi[gB]);
        *reinterpret_cast<int4*>(&Bl[0][cq][rr][0]) = *reinterpret_cast<const int4*>(&Alo[gB]);
    }

    f32x4 acc[4] = {};
    const int m = lane & 15;
    const int q = lane >> 4;
    const int KT = DD / TK;   // 16

    for (int kt = 0; kt < KT; ++kt) {
        const int cur = kt & 1;
        __syncthreads();   // buf[cur] staged; prior reads of buf[1-cur] retired
        if (kt + 1 < KT) {
            const size_t ko = (size_t)(kt + 1) * TK;
            const int nxt = 1 - cur;
            *reinterpret_cast<int4*>(&Ah[nxt][cq][rr][0]) = *reinterpret_cast<const int4*>(&Ahi[gA + ko]);
            *reinterpret_cast<int4*>(&Al[nxt][cq][rr][0]) = *reinterpret_cast<const int4*>(&Alo[gA + ko]);
            *reinterpret_cast<int4*>(&Bh[nxt][cq][rr][0]) = *reinterpret_cast<const int4*>(&Ahi[gB + ko]);
            *reinterpret_cast<int4*>(&Bl[nxt][cq][rr][0]) = *reinterpret_cast<const int4*>(&Alo[gB + ko]);
        }
        const s16x8 fah = *reinterpret_cast<const s16x8*>(&Ah[cur][q][w * 16 + m][0]);
        const s16x8 fal = *reinterpret_cast<const s16x8*>(&Al[cur][q][w * 16 + m][0]);
        s16x8 fbh[4], fbl[4];
        #pragma unroll
        for (int nt = 0; nt < 4; ++nt) {
            fbh[nt] = *reinterpret_cast<const s16x8*>(&Bh[cur][q][nt * 16 + m][0]);
            fbl[nt] = *reinterpret_cast<const s16x8*>(&Bl[cur][q][nt * 16 + m][0]);
        }
        #pragma unroll
        for (int nt = 0; nt < 4; ++nt) {
            acc[nt] = __builtin_amdgcn_mfma_f32_16x16x32_bf16(fah, fbh[nt], acc[nt], 0, 0, 0);
            acc[nt] = __builtin_amdgcn_mfma_f32_16x16x32_bf16(fah, fbl[nt], acc[nt], 0, 0, 0);
            acc[nt] = __builtin_amdgcn_mfma_f32_16x16x32_bf16(fal, fbh[nt], acc[nt], 0, 0, 0);
        }
    }

    const int lr0 = w * 16 + q * 4;
    #pragma unroll
    for (int nt = 0; nt < 4; ++nt) {
        const int lc = nt * 16 + m;
        float o[4];
        #pragma unroll
        for (int r = 0; r < 4; ++r) {
            const float d2 = sqA[lr0 + r] + sqB[lc] - 2.0f * acc[nt][r];
            o[r] = (d2 > 0.f) ? sqrtf(d2) : 0.f;
        }
        #pragma unroll
        for (int r = 0; r < 4; ++r)
            distp[(size_t)(row0 + lr0 + r) * NN + col0 + lc] = o[r];
        if (!diag) {
            const float4 o4 = make_float4(o[0], o[1], o[2], o[3]);
            *reinterpret_cast<float4*>(&distp[(size_t)(col0 + lc) * NN + row0 + lr0]) = o4;
        }
    }
}

// ---------------- kernel 3: row-pair scans + shared windows ----------------
__device__ __forceinline__ int bs_right(const float* key, float d, int lo, int hi) {
    while (lo < hi) {
        const int mid = (lo + hi) >> 1;
        if (key[mid] >= d) hi = mid; else lo = mid + 1;
    }
    return lo;
}
__device__ __forceinline__ int bs_left(const float* key, float d, int lo, int hi) {
    while (lo < hi) {
        const int mid = (lo + hi) >> 1;
        if (key[mid] < d) hi = mid; else lo = mid + 1;
    }
    return lo;
}

__global__ __launch_bounds__(256) void row_kernel(const float* __restrict__ distp,
                                                  const float* __restrict__ slab,
                                                  double* __restrict__ rowval) {
    __shared__ float key[NN];
    __shared__ float Pf[NN];
    __shared__ float Sf[NN + 1];
    __shared__ float wmxA[4], wmxB[4], wps[4], wss[4];
    __shared__ double wDA[4], wLA[4], wDB[4], wLB[4];

    const int pr = blockIdx.x;
    const int rA = 2 * pr, rB = 2 * pr + 1;
    const int t = threadIdx.x;
    const int lane = t & 63;
    const int w = t >> 6;
    const float x = slab[rA];
    const float negInvT = -1.0f / 0.07f;
    const float* drowA = &distp[(size_t)rA * NN];
    const float* drowB = &distp[(size_t)rB * NN];

    #pragma unroll
    for (int e = 0; e < 2; ++e) {
        const int p4 = t + e * NT;
        const float4 l4 = reinterpret_cast<const float4*>(slab)[p4];
        key[p4 * 4 + 0] = fabsf(l4.x - x);
        key[p4 * 4 + 1] = fabsf(l4.y - x);
        key[p4 * 4 + 2] = fabsf(l4.z - x);
        key[p4 * 4 + 3] = fabsf(l4.w - x);
    }
    const int cb = t * 8;
    float vA[8], vB[8];
    double dsumA = 0.0, dsumB = 0.0;
    float mxA = NEGINF, mxB = NEGINF;
    #pragma unroll
    for (int e = 0; e < 2; ++e) {
        const float4 a4 = reinterpret_cast<const float4*>(drowA)[2 * t + e];
        const float4 b4 = reinterpret_cast<const float4*>(drowB)[2 * t + e];
        const float av[4] = {a4.x, a4.y, a4.z, a4.w};
        const float bv[4] = {b4.x, b4.y, b4.z, b4.w};
        #pragma unroll
        for (int c = 0; c < 4; ++c) {
            const int pc = cb + e * 4 + c;
            if (pc == rA) vA[e * 4 + c] = NEGINF;
            else { const float vv = av[c] * negInvT; vA[e * 4 + c] = vv; mxA = fmaxf(mxA, vv); dsumA += (double)av[c]; }
            if (pc == rB) vB[e * 4 + c] = NEGINF;
            else { const float vv = bv[c] * negInvT; vB[e * 4 + c] = vv; mxB = fmaxf(mxB, vv); dsumB += (double)bv[c]; }
        }
    }
    #pragma unroll
    for (int st = 32; st > 0; st >>= 1) {
        mxA = fmaxf(mxA, __shfl_down(mxA, st));
        mxB = fmaxf(mxB, __shfl_down(mxB, st));
    }
    if (lane == 0) { wmxA[w] = mxA; wmxB[w] = mxB; }
    __syncthreads();   // B1
    const float MA = fmaxf(fmaxf(wmxA[0], wmxA[1]), fmaxf(wmxA[2], wmxA[3]));
    const float MB = fmaxf(fmaxf(wmxB[0], wmxB[1]), fmaxf(wmxB[2], wmxB[3]));

    // ---- window boundaries ONCE (shared by both rows) ----
    int L8[8], R8[8];
    const int a = cb, b = cb + 7;
    {
        const int le = (rA - 1 < b) ? rA - 1 : b;
        if (a <= le) {
            const float da = key[a];
            const int Ra = bs_right(key, da, rA, NN);
            int Rl = Ra;
            if (le > a) Rl = bs_right(key, key[le], rA, Ra);
            for (int p = a; p <= le; ++p) {
                const float d = key[p];
                int R;
                if (p == a) R = Ra;
                else if (p == le) R = Rl;
                else R = bs_right(key, d, Rl, Ra);
                int L = p + 1;
                while (L < rA && key[L] == d) ++L;
                L8[p - a] = L; R8[p - a] = R;
            }
        }
        const int rs = (rA + 1 > a) ? rA + 1 : a;
        if (rs <= b) {
            const float dr = key[rs];
            const int Lr = bs_left(key, dr, 0, rA);
            int Lb = Lr;
            if (b > rs) Lb = bs_left(key, key[b], 0, Lr);
            for (int p = rs; p <= b; ++p) {
                const float d = key[p];
                int L;
                if (p == rs) L = Lr;
                else if (p == b) L = Lb;
                else L = bs_left(key, d, Lb, Lr);
                int R = p;
                while (R > rA && key[R - 1] == d) --R;
                L8[p - a] = L; R8[p - a] = R;
            }
        }
        if (rA >= a && rA <= b) { L8[rA - a] = rA; R8[rA - a] = rA; }
    }

    // ================= row A =================
    double lnsumA = 0.0;
    {
        float e8[8];
        #pragma unroll
        for (int jj = 0; jj < 8; ++jj) e8[jj] = __expf(vA[jj] - MA + CS);
        {
            float run = 0.f, ex[8];
            #pragma unroll
            for (int jj = 0; jj < 8; ++jj) { ex[jj] = run; run += e8[jj]; }
            float inc = run;
            #pragma unroll
            for (int st = 1; st < 64; st <<= 1) {
                const float nm = __shfl_up(inc, st);
                if (lane >= st) inc += nm;
            }
            float xofs = __shfl_up(inc, 1);
            if (lane == 0) xofs = 0.f;
            if (lane == 63) wps[w] = inc;
            __syncthreads();   // B2
            #pragma unroll
            for (int ww = 0; ww < 3; ++ww)
                if (ww < w) xofs += wps[ww];
            #pragma unroll
            for (int jj = 0; jj < 8; ++jj) Pf[cb + jj] = ex[jj] + xofs;
        }
        {
            float run = 0.f, sx[8];
            #pragma unroll
            for (int jj = 7; jj >= 0; --jj) { run += e8[jj]; sx[jj] = run; }
            float inc = run;
            #pragma unroll
            for (int st = 1; st < 64; st <<= 1) {
                const float nm = __shfl_down(inc, st);
                if (lane + st < 64) inc += nm;
            }
            float xofs = __shfl_down(inc, 1);
            if (lane == 63) xofs = 0.f;
            if (lane == 0) wss[w] = inc;
            __syncthreads();   // B3
            #pragma unroll
            for (int ww = 1; ww < 4; ++ww)
                if (ww > w) xofs += wss[ww];
            #pragma unroll
            for (int jj = 0; jj < 8; ++jj) Sf[cb + jj] = sx[jj] + xofs;
            if (t == 0) Sf[NN] = 0.f;
        }
        __syncthreads();   // B4
        const float MBA = MA - CS;
        #pragma unroll
        for (int jj = 0; jj < 8; ++jj) {
            const int p = cb + jj;
            if (p == rA) continue;
            const float s = fmaxf(Pf[L8[jj]] + Sf[R8[jj]], 1e-38f);
            lnsumA += (double)(MBA + __logf(s));
        }
    }
    __syncthreads();   // B5

    // ================= row B =================
    double lnsumB = 0.0;
    {
        float e8[8];
        #pragma unroll
        for (int jj = 0; jj < 8; ++jj) e8[jj] = __expf(vB[jj] - MB + CS);
        {
            float run = 0.f, ex[8];
            #pragma unroll
            for (int jj = 0; jj < 8; ++jj) { ex[jj] = run; run += e8[jj]; }
            float inc = run;
            #pragma unroll
            for (int st = 1; st < 64; st <<= 1) {
                const float nm = __shfl_up(inc, st);
                if (lane >= st) inc += nm;
            }
            float xofs = __shfl_up(inc, 1);
            if (lane == 0) xofs = 0.f;
            if (lane == 63) wps[w] = inc;
            __syncthreads();   // B6
            #pragma unroll
            for (int ww = 0; ww < 3; ++ww)
                if (ww < w) xofs += wps[ww];
            #pragma unroll
            for (int jj = 0; jj < 8; ++jj) Pf[cb + jj] = ex[jj] + xofs;
        }
        {
            float run = 0.f, sx[8];
            #pragma unroll
            for (int jj = 7; jj >= 0; --jj) { run += e8[jj]; sx[jj] = run; }
            float inc = run;
            #pragma unroll
            for (int st = 1; st < 64; st <<= 1) {
                const float nm = __shfl_down(inc, st);
                if (lane + st < 64) inc += nm;
            }
            float xofs = __shfl_down(inc, 1);
            if (lane == 63) xofs = 0.f;
            if (lane == 0) wss[w] = inc;
            __syncthreads();   // B7
            #pragma unroll
            for (int ww = 1; ww < 4; ++ww)
                if (ww > w) xofs += wss[ww];
            #pragma unroll
            for (int jj = 0; jj < 8; ++jj) Sf[cb + jj] = sx[jj] + xofs;
            if (t == 0) Sf[NN] = 0.f;
        }
        __syncthreads();   // B8
        const float MBB = MB - CS;
        #pragma unroll
        for (int jj = 0; jj < 8; ++jj) {
            const int p = cb + jj;
            if (p == rB) continue;
            const float s = fmaxf(Pf[L8[jj]] + Sf[R8[jj]], 1e-38f);
            lnsumB += (double)(MBB + __logf(s));
        }
    }

    // ---- reductions ----
    #pragma unroll
    for (int st = 32; st > 0; st >>= 1) {
        dsumA  += __shfl_down(dsumA, st);
        lnsumA += __shfl_down(lnsumA, st);
        dsumB  += __shfl_down(dsumB, st);
        lnsumB += __shfl_down(lnsumB, st);
    }
    if (lane == 0) { wDA[w] = dsumA; wLA[w] = lnsumA; wDB[w] = dsumB; wLB[w] = lnsumB; }
    __syncthreads();   // B9
    if (t == 0) {
        rowval[rA] = (-(wDA[0] + wDA[1] + wDA[2] + wDA[3]) / 0.07)
                   - (wLA[0] + wLA[1] + wLA[2] + wLA[3]);
        rowval[rB] = (-(wDB[0] + wDB[1] + wDB[2] + wDB[3]) / 0.07)
                   - (wLB[0] + wLB[1] + wLB[2] + wLB[3]);
    }
}

// ---------------- kernel 4: final mean ----------------
__global__ __launch_bounds__(256) void finalize_kernel(const double* __restrict__ rowval,
                                                       float* __restrict__ out) {
    __shared__ double red[NT];
    const int t = threadIdx.x;
    double s = 0.0;
    for (int j = t; j < NN; j += NT) s += rowval[j];
    red[t] = s;
    __syncthreads();
    for (int ofs = NT / 2; ofs > 0; ofs >>= 1) {
        if (t < ofs) red[t] += red[t + ofs];
        __syncthreads();
    }
    if (t == 0) {
        out[0] = (float)(-red[0] / ((double)NN * (double)(NN - 1)));
    }
}

extern "C" void kernel_launch(void* const* d_in, const int* in_sizes, int n_in,
                              void* d_out, int out_size, void* d_ws, size_t ws_size,
                              hipStream_t stream) {
    const float* features = (const float*)d_in[0];  // [1024, 2, 512] fp32
    const float* labels   = (const float*)d_in[1];  // [1024] fp32
    float* out = (float*)d_out;

    char* ws = (char*)d_ws;
    size_t off = 0;
    float*  sq     = (float*) (ws + off); off += NN * sizeof(float);
    float*  slab   = (float*) (ws + off); off += NN * sizeof(float);
    int*    sj     = (int*)   (ws + off); off += NN * sizeof(int);
    double* rowval = (double*)(ws + off); off += NN * sizeof(double);
    ushort* Ahi    = (ushort*)(ws + off); off += (size_t)NN * DD * sizeof(ushort);
    ushort* Alo    = (ushort*)(ws + off); off += (size_t)NN * DD * sizeof(ushort);
    float*  distp  = (float*) (ws + off); off += (size_t)NN * NN * sizeof(float);

    prep_kernel<<<NPREP + 4, NT, 0, stream>>>(features, labels, Ahi, Alo, sq, slab, sj);
    gemm_dist_kernel<<<32 * 33 / 2, NT, 0, stream>>>(Ahi, Alo, sq, sj, distp);
    row_kernel<<<NN / 2, NT, 0, stream>>>(distp, slab, rowval);
    finalize_kernel<<<1, NT, 0, stream>>>(rowval, out);
}